// Round 10
// baseline (829.063 us; speedup 1.0000x reference)
//
#include <hip/hip_runtime.h>
#include <hip/hip_cooperative_groups.h>

namespace cg = cooperative_groups;

typedef unsigned char u8;
typedef unsigned short u16;
typedef unsigned int u32;
typedef unsigned long long u64;

#define NN 4096
#define NITER 50
#define REGE 10.0f
#define AMARG (1.0f / 4096.0f)
#define NB 256
#define KSCL 4096.0f             // K stored as Q = K * 2^12 in fp8-e5m2
#define KLN2 8.317766166719343f  // 12 * ln(2)

__device__ __forceinline__ float wsum(float v) {
#pragma unroll
    for (int off = 32; off; off >>= 1) v += __shfl_xor(v, off, 64);
    return v;
}
// e5m2 encode: f32 -> f16 (RNE) -> round mantissa to 2 bits (RNE).
__device__ __forceinline__ u8 f2e5(float f) {
    union { _Float16 h; u16 u; } cv; cv.h = (_Float16)f;
    const u16 h = cv.u;
    return (u8)((h + 0x7F + ((h >> 8) & 1)) >> 8);
}
// e5m2 = truncated fp16. Decode 4 bytes: v_perm to [0,b0,0,b1]/[0,b2,0,b3],
// then paired f16->f32 cvt. Exact incl. subnormals.
typedef _Float16 h2v __attribute__((ext_vector_type(2)));
__device__ __forceinline__ void dec4(u32 w, float* o) {
    const u32 h01 = __builtin_amdgcn_perm(0u, w, 0x01040004u);
    const u32 h23 = __builtin_amdgcn_perm(0u, w, 0x03040204u);
    const h2v p01 = __builtin_bit_cast(h2v, h01);
    const h2v p23 = __builtin_bit_cast(h2v, h23);
    o[0] = (float)p01.x; o[1] = (float)p01.y;
    o[2] = (float)p23.x; o[3] = (float)p23.y;
}

// Agent-scope (L1/L2-bypassing, L3-coherent) ops; RELAXED => no cache
// maintenance => private K regions stay L2-resident.
__device__ __forceinline__ float agent_ldf(const float* p) {
    return __hip_atomic_load(p, __ATOMIC_RELAXED, __HIP_MEMORY_SCOPE_AGENT);
}
__device__ __forceinline__ void agent_stf(float* p, float v) {
    __hip_atomic_store(p, v, __ATOMIC_RELAXED, __HIP_MEMORY_SCOPE_AGENT);
}
__device__ __forceinline__ int agent_ldi(const int* p) {
    return __hip_atomic_load(p, __ATOMIC_RELAXED, __HIP_MEMORY_SCOPE_AGENT);
}
__device__ __forceinline__ void agent_sti(int* p, int v) {
    __hip_atomic_store(p, v, __ATOMIC_RELAXED, __HIP_MEMORY_SCOPE_AGENT);
}
__device__ __forceinline__ u64 agent_ld64(const u64* p) {
    return __hip_atomic_load(p, __ATOMIC_RELAXED, __HIP_MEMORY_SCOPE_AGENT);
}
__device__ __forceinline__ void agent_st64(u64* p, u64 v) {
    __hip_atomic_store(p, v, __ATOMIC_RELAXED, __HIP_MEMORY_SCOPE_AGENT);
}
__device__ __forceinline__ u64 pk(float v, u32 tag) {
    return ((u64)tag << 32) | (u64)__float_as_uint(v);
}
__device__ __forceinline__ float upv(u64 w) { return __uint_as_float((u32)w); }
__device__ __forceinline__ u32 uptag(u64 w) { return (u32)(w >> 32); }

// publish: __syncthreads drains every wave's sc1 stores (compiler emits
// vmcnt(0) before s_barrier), then ONE plain epoch store — no atomic RMW,
// so no same-line far-atomic convoy (R9 lesson).
__device__ __forceinline__ void publish(int* f, int v, int tid) {
    __syncthreads();
    if (tid == 0) {
        asm volatile("s_waitcnt vmcnt(0)" ::: "memory");
        agent_sti(f, v);
    }
}
// pollN: ONE thread polls N contiguous epoch flags (>= target; monotone, no
// reset) as a load clause. Single poller per block (R8 lesson).
template <int N>
__device__ __forceinline__ void pollN(const int* f, int target, int tid) {
    if (tid == 0) {
        for (;;) {
            int mn = 0x7fffffff;
#pragma unroll
            for (int i = 0; i < N; ++i) mn = min(mn, agent_ldi(f + i));
            if (mn >= target) break;
            __builtin_amdgcn_s_sleep(1);
        }
    }
    __syncthreads();
}

__global__ __launch_bounds__(1024, 4) void sinkhorn_all(
    const float* __restrict__ x, const float* __restrict__ y, float* __restrict__ out,
    u8* __restrict__ K0,
    float* __restrict__ xsq, float* __restrict__ ysq,
    float* __restrict__ tpart, float* __restrict__ spart,
    u64* __restrict__ lossq, int* __restrict__ bar) {
    cg::grid_group grid = cg::this_grid();
    union Sh {
        struct { float xs[64][65]; float ys[64][65]; } bld;   // setup tiles (33 KB)
        struct {
            float uts[512];             // ut stripe slice (combined locally)
            float psumA[16][16][9];     // A: per-wave partials (bank-spread pad)
            float vtl[128];             // vt chunk (persists A->B->F)
            float psh[16];              // F: per-wave partials
        } it;                           // ~12 KB
    };
    __shared__ Sh sh;

    const int tid  = threadIdx.x;
    const int lane = tid & 63;
    const int wid  = tid >> 6;     // 0..15
    const int b    = blockIdx.x;
    const int c    = b & 7;        // stripe: rows [512c, 512c+512)
    const int l    = b >> 3;       // 0..31: col-chunk [128l, 128l+128)

    // bar (ints): tpf[32][8] @0 | spf[8][32] @256  (per-producer epoch flags)
    int* tpf = bar + l * 8;          // flags for chunk l (producers c=0..7)
    int* spf = bar + 256 + c * 32;   // flags for stripe c (producers l=0..31)

    // ---------------- S0: row norms + init ----------------
    for (int r = b * 16 + wid; r < 2 * NN; r += NB * 16) {
        const float* src = (r < NN) ? (x + (size_t)r * 64) : (y + (size_t)(r - NN) * 64);
        float t = src[lane];
        float s = wsum(t * t);
        if (lane == 0) { if (r < NN) xsq[r] = s; else ysq[r - NN] = s; }
    }
    if (b == 0 && tid < 512) bar[tid] = 0;
    if (tid == 0) lossq[b] = 0ull;
    grid.sync();   // the ONLY grid barrier: init visible, poison cleared

    // ---- S1: build Q = K*2^12 = exp2(12 - M*log2e/10) e5m2, region-private ----
    {
        const int tx = tid & 31, ty = tid >> 5;   // 32x32 threads, 2x2 out each
        for (int rt = 0; rt < 8; ++rt) {
            const int i0 = 512 * c + 64 * rt;
            __syncthreads();
            {
                const int row = tid >> 4, col4 = (tid & 15) * 4;
                *(float4*)&sh.bld.xs[row][col4] = *(const float4*)(x + (size_t)(i0 + row) * 64 + col4);
            }
            for (int ct = 0; ct < 2; ++ct) {
                const int j0 = 128 * l + 64 * ct;
                __syncthreads();
                {
                    const int row = tid >> 4, col4 = (tid & 15) * 4;
                    *(float4*)&sh.bld.ys[row][col4] = *(const float4*)(y + (size_t)(j0 + row) * 64 + col4);
                }
                __syncthreads();
                float a00 = 0, a01 = 0, a10 = 0, a11 = 0;
#pragma unroll
                for (int k = 0; k < 64; ++k) {
                    const float x0 = sh.bld.xs[ty * 2][k],     x1 = sh.bld.xs[ty * 2 + 1][k];
                    const float y0 = sh.bld.ys[tx * 2][k],     y1 = sh.bld.ys[tx * 2 + 1][k];
                    a00 = __fmaf_rn(x0, y0, a00); a01 = __fmaf_rn(x0, y1, a01);
                    a10 = __fmaf_rn(x1, y0, a10); a11 = __fmaf_rn(x1, y1, a11);
                }
                const float xq0 = xsq[i0 + ty * 2], xq1 = xsq[i0 + ty * 2 + 1];
                const float yq0 = ysq[j0 + tx * 2], yq1 = ysq[j0 + tx * 2 + 1];
                const float C = 0.14426950408889634f;   // log2(e)/10
                const u8 q00 = f2e5(exp2f(12.f - (xq0 + yq0 - 2.f * a00) * C));
                const u8 q01 = f2e5(exp2f(12.f - (xq0 + yq1 - 2.f * a01) * C));
                const u8 q10 = f2e5(exp2f(12.f - (xq1 + yq0 - 2.f * a10) * C));
                const u8 q11 = f2e5(exp2f(12.f - (xq1 + yq1 - 2.f * a11) * C));
                // plain stores: region is block-private => stays in this XCD's L2
                *(u16*)(K0 + (size_t)(i0 + ty * 2) * NN + j0 + tx * 2)     = (u16)(q00 | (q01 << 8));
                *(u16*)(K0 + (size_t)(i0 + ty * 2 + 1) * NN + j0 + tx * 2) = (u16)(q10 | (q11 << 8));
            }
        }
    }
    // no sync: only this block reads its region

    // ------- 50 iterations: 2 flag chains per iteration, zero atomics -------
    for (int n = 0; n < NITER; ++n) {
        const int p = n & 1;   // parity for this iter's tpart & spart

        // ---- A: prefetch private K rows (in flight during the spf wait) ----
        const int jj = tid & 15, gg = tid >> 4;   // 8 cols x 8 rows per thread
        const u8* kbase = K0 + (size_t)(512 * c + 8 * gg) * NN + 128 * l + 8 * jj;
        uint2 kr[8];
#pragma unroll
        for (int ii = 0; ii < 8; ++ii)
            kr[ii] = *(const uint2*)(kbase + (size_t)ii * NN);

        // ---- ut combine (reader-side; ut never hits global memory) ----
        if (n == 0) {
            if (tid < 512) sh.it.uts[tid] = AMARG;   // u~(0) = a
            __syncthreads();
        } else {
            pollN<32>(spf, n, tid);                  // stripe-c B(n-1) all done
            const float* sp = spart + (size_t)(((n - 1) & 1) * 8 + c) * 16384;
            const int r = tid >> 1, h = tid & 1;
            float acc = 0.f;
#pragma unroll
            for (int lp = 0; lp < 16; ++lp)
                acc += agent_ldf(sp + (16 * h + lp) * 512 + r);
            acc += __shfl_xor(acc, 1, 64);
            if (h == 0) sh.it.uts[r] = 1.0f / acc;   // ut_i (stateless scaled vars)
            __syncthreads();
        }

        // ---- A compute: col partials t_j over region rows ----
        {
            float acc[8] = {};
#pragma unroll
            for (int ii = 0; ii < 8; ++ii) {
                const float ui = sh.it.uts[8 * gg + ii];
                float qv[8];
                dec4(kr[ii].x, qv); dec4(kr[ii].y, qv + 4);
#pragma unroll
                for (int k = 0; k < 8; ++k) acc[k] = __fmaf_rn(qv[k], ui, acc[k]);
            }
#pragma unroll
            for (int k = 0; k < 8; ++k) {             // combine 4 row-groups in wave
                acc[k] += __shfl_xor(acc[k], 16, 64);
                acc[k] += __shfl_xor(acc[k], 32, 64);
            }
            if ((lane >> 4) == 0) {
#pragma unroll
                for (int k = 0; k < 8; ++k) sh.it.psumA[wid][lane][k] = acc[k];
            }
        }
        __syncthreads();
        if (tid < 128) {
            float tot = 0.f;
#pragma unroll
            for (int w = 0; w < 16; ++w) tot += sh.it.psumA[w][tid >> 3][tid & 7];
            agent_stf(tpart + (size_t)(p * 8 + c) * 4096 + 128 * l + tid, tot);
        }

        // ---- B: prefetch private K (contiguous rows) before tpf chain ----
        const int r = tid >> 1, h = tid & 1;          // 2 threads/row, 64 cols each
        const u8* kb = K0 + (size_t)(512 * c + r) * NN + 128 * l + 64 * h;
        uint4 kq[4];
#pragma unroll
        for (int s4 = 0; s4 < 4; ++s4)
            kq[s4] = *(const uint4*)(kb + s4 * 16);

        publish(tpf + c, n + 1, tid);                 // my stripe partial ready
        pollN<8>(tpf, n + 1, tid);                    // all 8 stripe partials ready
        if (tid < 128) {
            const float* tb = tpart + (size_t)p * 32768 + 128 * l + tid;
            float tq = 0.f;
#pragma unroll
            for (int cc = 0; cc < 8; ++cc) tq += agent_ldf(tb + cc * 4096);
            sh.it.vtl[tid] = 1.0f / tq;               // vt_j
        }
        __syncthreads();

        // ---- B compute: row partials s_i; coalesced parity store ----
        {
            float s = 0.f;
#pragma unroll
            for (int s4 = 0; s4 < 4; ++s4) {
                float qv[16];
                dec4(kq[s4].x, qv);      dec4(kq[s4].y, qv + 4);
                dec4(kq[s4].z, qv + 8);  dec4(kq[s4].w, qv + 12);
                const float* vp = &sh.it.vtl[64 * h + s4 * 16];
#pragma unroll
                for (int k = 0; k < 16; ++k) s = __fmaf_rn(qv[k], vp[k], s);
            }
            s += __shfl_xor(s, 1, 64);
            if (h == 0)   // even lanes: 32 consecutive floats per wave (coalesced)
                agent_stf(spart + (size_t)(p * 8 + c) * 16384 + l * 512 + r, s);
        }
        publish(spf + l, n + 1, tid);                 // my chunk partial ready
    }

    // ------ F: loss = sum_ij K*(-eps log K)*ut_i*vt_j over own region ------
    // per element: (-eps/KSCL) * Q*(lnQ - 12ln2) * ut_i * vt_j
    pollN<32>(spf, NITER, tid);
    {
        const float* sp = spart + (size_t)(((NITER - 1) & 1) * 8 + c) * 16384;
        const int r = tid >> 1, h = tid & 1;
        float acc = 0.f;
#pragma unroll
        for (int lp = 0; lp < 16; ++lp)
            acc += agent_ldf(sp + (16 * h + lp) * 512 + r);
        acc += __shfl_xor(acc, 1, 64);
        if (h == 0) sh.it.uts[r] = 1.0f / acc;        // final ut
    }
    __syncthreads();
    {
        const int r = tid >> 1, h = tid & 1;
        const u8* kb = K0 + (size_t)(512 * c + r) * NN + 128 * l + 64 * h;
        uint4 kq[4];
#pragma unroll
        for (int s4 = 0; s4 < 4; ++s4)
            kq[s4] = *(const uint4*)(kb + s4 * 16);
        float a1 = 0.f, a2 = 0.f;
#pragma unroll
        for (int s4 = 0; s4 < 4; ++s4) {
            float qv[16];
            dec4(kq[s4].x, qv);      dec4(kq[s4].y, qv + 4);
            dec4(kq[s4].z, qv + 8);  dec4(kq[s4].w, qv + 12);
            const float* vp = &sh.it.vtl[64 * h + s4 * 16];
#pragma unroll
            for (int k = 0; k < 16; ++k) {
                const float q = qv[k];
                a2 = __fmaf_rn(q, vp[k], a2);
                a1 = __fmaf_rn(q * __logf(fmaxf(q, 1e-30f)), vp[k], a1);  // q=0 -> 0
            }
        }
        a1 += __shfl_xor(a1, 1, 64);
        a2 += __shfl_xor(a2, 1, 64);
        float rowv = (h == 0) ? (a1 - KLN2 * a2) * sh.it.uts[r] : 0.f;
        rowv = wsum(rowv);
        if (lane == 0) sh.it.psh[wid] = rowv;
    }
    __syncthreads();
    // ---- finale: tagged per-block slots, one poller (no 256-RMW convoy) ----
    if (tid == 0) {
        float bacc = 0.f;
#pragma unroll
        for (int w = 0; w < 16; ++w) bacc += sh.it.psh[w];
        agent_st64(lossq + b, pk(bacc, 1u));
        if (b == 0) {
            float tot;
            for (;;) {
                bool ok = true;
                float s = 0.f;
                for (int i = 0; i < NB; ++i) {
                    const u64 v = agent_ld64(lossq + i);
                    ok &= (uptag(v) == 1u);
                    s += upv(v);
                }
                if (ok) { tot = s; break; }
                __builtin_amdgcn_s_sleep(1);
            }
            agent_stf(out, tot * (-REGE / KSCL));
        }
    }
}

extern "C" void kernel_launch(void* const* d_in, const int* in_sizes, int n_in,
                              void* d_out, int out_size, void* d_ws, size_t ws_size,
                              hipStream_t stream) {
    const float* x = (const float*)d_in[0];
    const float* y = (const float*)d_in[1];
    float* out = (float*)d_out;
    char* ws = (char*)d_ws;

    // ws: K0 e5m2 16MB | xsq,ysq 4096 f32 | tpart 2x8x4096 f32 | spart 2x8x32x512 f32
    //     | lossq 256 u64 | bar 512 ints
    u8* K0 = (u8*)(ws);
    float* xsq = (float*)(ws + 16777216ull);
    float* ysq = xsq + 4096;
    float* tpart = ysq + 4096;             // 65536 floats (2 parities)
    float* spart = tpart + 65536;          // 262144 floats (2 parities)
    u64* lossq = (u64*)(spart + 262144);   // 256 tagged slots
    int* bar = (int*)(lossq + 256);        // 512 epoch flags

    void* args[] = {&x, &y, &out, &K0, &xsq, &ysq, &tpart, &spart, &lossq, &bar};

    hipError_t err = hipLaunchCooperativeKernel((void*)sinkhorn_all, dim3(NB), dim3(1024),
                                                (void**)args, 0, stream);
    if (err != hipSuccess)
        (void)hipLaunchCooperativeKernel((void*)sinkhorn_all, dim3(NB), dim3(1024),
                                         (void**)args, 0, stream);
}

// Round 11
// 700.847 us; speedup vs baseline: 1.1829x; 1.1829x over previous
//
#include <hip/hip_runtime.h>
#include <hip/hip_cooperative_groups.h>

namespace cg = cooperative_groups;

typedef unsigned char u8;
typedef unsigned short u16;
typedef unsigned int u32;
typedef unsigned long long u64;

#define NN 4096
#define NITER 50
#define REGE 10.0f
#define AMARG (1.0f / 4096.0f)
#define NB 256
#define KSCL 4096.0f             // K stored as Q = K * 2^12 in fp8-e5m2
#define KLN2 8.317766166719343f  // 12 * ln(2)

__device__ __forceinline__ float wsum(float v) {
#pragma unroll
    for (int off = 32; off; off >>= 1) v += __shfl_xor(v, off, 64);
    return v;
}
// e5m2 encode: f32 -> f16 (RNE) -> round mantissa to 2 bits (RNE).
__device__ __forceinline__ u8 f2e5(float f) {
    union { _Float16 h; u16 u; } cv; cv.h = (_Float16)f;
    const u16 h = cv.u;
    return (u8)((h + 0x7F + ((h >> 8) & 1)) >> 8);
}
// e5m2 = truncated fp16. Decode 4 bytes: v_perm to [0,b0,0,b1]/[0,b2,0,b3],
// then paired f16->f32 cvt. Exact incl. subnormals.
typedef _Float16 h2v __attribute__((ext_vector_type(2)));
__device__ __forceinline__ void dec4(u32 w, float* o) {
    const u32 h01 = __builtin_amdgcn_perm(0u, w, 0x01040004u);
    const u32 h23 = __builtin_amdgcn_perm(0u, w, 0x03040204u);
    const h2v p01 = __builtin_bit_cast(h2v, h01);
    const h2v p23 = __builtin_bit_cast(h2v, h23);
    o[0] = (float)p01.x; o[1] = (float)p01.y;
    o[2] = (float)p23.x; o[3] = (float)p23.y;
}

// Agent-scope (L1/L2-bypassing, L3-coherent) ops; RELAXED => no cache
// maintenance => private K regions stay L2-resident.
__device__ __forceinline__ float agent_ldf(const float* p) {
    return __hip_atomic_load(p, __ATOMIC_RELAXED, __HIP_MEMORY_SCOPE_AGENT);
}
__device__ __forceinline__ void agent_stf(float* p, float v) {
    __hip_atomic_store(p, v, __ATOMIC_RELAXED, __HIP_MEMORY_SCOPE_AGENT);
}
__device__ __forceinline__ int agent_ldi(const int* p) {
    return __hip_atomic_load(p, __ATOMIC_RELAXED, __HIP_MEMORY_SCOPE_AGENT);
}
__device__ __forceinline__ void agent_sti(int* p, int v) {
    __hip_atomic_store(p, v, __ATOMIC_RELAXED, __HIP_MEMORY_SCOPE_AGENT);
}
__device__ __forceinline__ u64 agent_ld64(const u64* p) {
    return __hip_atomic_load(p, __ATOMIC_RELAXED, __HIP_MEMORY_SCOPE_AGENT);
}
__device__ __forceinline__ void agent_st64(u64* p, u64 v) {
    __hip_atomic_store(p, v, __ATOMIC_RELAXED, __HIP_MEMORY_SCOPE_AGENT);
}
__device__ __forceinline__ u64 pk(float v, u32 tag) {
    return ((u64)tag << 32) | (u64)__float_as_uint(v);
}
__device__ __forceinline__ float upv(u64 w) { return __uint_as_float((u32)w); }
__device__ __forceinline__ u32 uptag(u64 w) { return (u32)(w >> 32); }

// publish: __syncthreads drains every wave's sc1 stores (compiler emits
// vmcnt(0) before s_barrier), then ONE plain epoch store to this producer's
// PRIVATE 128-B line — producers' publishes proceed in parallel (R10 lesson:
// same-line stores serialize exactly like RMWs).
__device__ __forceinline__ void publish(int* f, int v, int tid) {
    __syncthreads();
    if (tid == 0) {
        asm volatile("s_waitcnt vmcnt(0)" ::: "memory");
        agent_sti(f, v);
    }
}
// pollF: ONE thread polls N flags spaced 32 ints (128 B) apart as one load
// clause (single poller per block — R8 lesson). Monotone epochs, no reset.
template <int N>
__device__ __forceinline__ void pollF(const int* f, int target, int tid) {
    if (tid == 0) {
        for (;;) {
            int mn = 0x7fffffff;
#pragma unroll
            for (int i = 0; i < N; ++i) mn = min(mn, agent_ldi(f + i * 32));
            if (mn >= target) break;
            __builtin_amdgcn_s_sleep(1);
        }
    }
    __syncthreads();
}

__global__ __launch_bounds__(1024, 4) void sinkhorn_all(
    const float* __restrict__ x, const float* __restrict__ y, float* __restrict__ out,
    u8* __restrict__ K0,
    float* __restrict__ xsq, float* __restrict__ ysq,
    float* __restrict__ tpart, float* __restrict__ spart,
    u64* __restrict__ lossq, int* __restrict__ bar) {
    cg::grid_group grid = cg::this_grid();
    union Sh {
        struct { float xs[64][65]; float ys[64][65]; } bld;   // setup tiles (33 KB)
        struct {
            float uts[512];             // ut stripe slice (combined locally)
            float psumA[16][16][9];     // A: per-wave partials (bank-spread pad)
            float vtl[128];             // vt chunk (persists A->B->F)
            float psh[16];              // F: per-wave partials
        } it;                           // ~12 KB
    };
    __shared__ Sh sh;

    const int tid  = threadIdx.x;
    const int lane = tid & 63;
    const int wid  = tid >> 6;     // 0..15
    const int b    = blockIdx.x;
    const int c    = b & 7;        // stripe: rows [512c, 512c+512)
    const int l    = b >> 3;       // 0..31: col-chunk [128l, 128l+128)

    // bar (ints): tpf[32][8] lines @0 (each flag on own 128-B line) |
    //             spf[8][32] lines @8192
    int* tpf   = bar + l * 8 * 32;           // 8 producer flags for chunk l
    int* spf   = bar + 8192 + c * 32 * 32;   // 32 producer flags for stripe c
    int* mytpf = tpf + c * 32;               // this block's flags
    int* myspf = spf + l * 32;

    // ---------------- S0: row norms + init (each block owns its flags) ----
    for (int r = b * 16 + wid; r < 2 * NN; r += NB * 16) {
        const float* src = (r < NN) ? (x + (size_t)r * 64) : (y + (size_t)(r - NN) * 64);
        float t = src[lane];
        float s = wsum(t * t);
        if (lane == 0) { if (r < NN) xsq[r] = s; else ysq[r - NN] = s; }
    }
    if (tid == 0) { *mytpf = 0; *myspf = 0; lossq[b * 16] = 0ull; }
    grid.sync();   // the ONLY grid barrier: init visible, poison cleared

    // ---- S1: build Q = K*2^12 = exp2(12 - M*log2e/10) e5m2, region-private ----
    {
        const int tx = tid & 31, ty = tid >> 5;   // 32x32 threads, 2x2 out each
        for (int rt = 0; rt < 8; ++rt) {
            const int i0 = 512 * c + 64 * rt;
            __syncthreads();
            {
                const int row = tid >> 4, col4 = (tid & 15) * 4;
                *(float4*)&sh.bld.xs[row][col4] = *(const float4*)(x + (size_t)(i0 + row) * 64 + col4);
            }
            for (int ct = 0; ct < 2; ++ct) {
                const int j0 = 128 * l + 64 * ct;
                __syncthreads();
                {
                    const int row = tid >> 4, col4 = (tid & 15) * 4;
                    *(float4*)&sh.bld.ys[row][col4] = *(const float4*)(y + (size_t)(j0 + row) * 64 + col4);
                }
                __syncthreads();
                float a00 = 0, a01 = 0, a10 = 0, a11 = 0;
#pragma unroll
                for (int k = 0; k < 64; ++k) {
                    const float x0 = sh.bld.xs[ty * 2][k],     x1 = sh.bld.xs[ty * 2 + 1][k];
                    const float y0 = sh.bld.ys[tx * 2][k],     y1 = sh.bld.ys[tx * 2 + 1][k];
                    a00 = __fmaf_rn(x0, y0, a00); a01 = __fmaf_rn(x0, y1, a01);
                    a10 = __fmaf_rn(x1, y0, a10); a11 = __fmaf_rn(x1, y1, a11);
                }
                const float xq0 = xsq[i0 + ty * 2], xq1 = xsq[i0 + ty * 2 + 1];
                const float yq0 = ysq[j0 + tx * 2], yq1 = ysq[j0 + tx * 2 + 1];
                const float C = 0.14426950408889634f;   // log2(e)/10
                const u8 q00 = f2e5(exp2f(12.f - (xq0 + yq0 - 2.f * a00) * C));
                const u8 q01 = f2e5(exp2f(12.f - (xq0 + yq1 - 2.f * a01) * C));
                const u8 q10 = f2e5(exp2f(12.f - (xq1 + yq0 - 2.f * a10) * C));
                const u8 q11 = f2e5(exp2f(12.f - (xq1 + yq1 - 2.f * a11) * C));
                // plain stores: region is block-private => stays in this XCD's L2
                *(u16*)(K0 + (size_t)(i0 + ty * 2) * NN + j0 + tx * 2)     = (u16)(q00 | (q01 << 8));
                *(u16*)(K0 + (size_t)(i0 + ty * 2 + 1) * NN + j0 + tx * 2) = (u16)(q10 | (q11 << 8));
            }
        }
    }
    // no sync: only this block reads its region

    // ------- 50 iterations: 2 flag chains/iter, all signals line-parallel -------
    for (int n = 0; n < NITER; ++n) {
        const int p = n & 1;   // parity for this iter's tpart & spart

        // ---- A: prefetch private K rows (in flight during the spf wait) ----
        const int jj = tid & 15, gg = tid >> 4;   // 8 cols x 8 rows per thread
        const u8* kbase = K0 + (size_t)(512 * c + 8 * gg) * NN + 128 * l + 8 * jj;
        uint2 kr[8];
#pragma unroll
        for (int ii = 0; ii < 8; ++ii)
            kr[ii] = *(const uint2*)(kbase + (size_t)ii * NN);

        // ---- ut combine (reader-side; ut never hits global memory) ----
        if (n == 0) {
            if (tid < 512) sh.it.uts[tid] = AMARG;   // u~(0) = a
            __syncthreads();
        } else {
            pollF<32>(spf, n, tid);                  // stripe-c B(n-1) all done
            const float* sp = spart + (size_t)(((n - 1) & 1) * 8 + c) * 16384;
            const int r = tid >> 1, h = tid & 1;
            float acc = 0.f;
#pragma unroll
            for (int lp = 0; lp < 16; ++lp)
                acc += agent_ldf(sp + (16 * h + lp) * 512 + r);
            acc += __shfl_xor(acc, 1, 64);
            if (h == 0) sh.it.uts[r] = 1.0f / acc;   // ut_i (stateless scaled vars)
            __syncthreads();
        }

        // ---- A compute: col partials t_j over region rows ----
        {
            float acc[8] = {};
#pragma unroll
            for (int ii = 0; ii < 8; ++ii) {
                const float ui = sh.it.uts[8 * gg + ii];
                float qv[8];
                dec4(kr[ii].x, qv); dec4(kr[ii].y, qv + 4);
#pragma unroll
                for (int k = 0; k < 8; ++k) acc[k] = __fmaf_rn(qv[k], ui, acc[k]);
            }
#pragma unroll
            for (int k = 0; k < 8; ++k) {             // combine 4 row-groups in wave
                acc[k] += __shfl_xor(acc[k], 16, 64);
                acc[k] += __shfl_xor(acc[k], 32, 64);
            }
            if ((lane >> 4) == 0) {
#pragma unroll
                for (int k = 0; k < 8; ++k) sh.it.psumA[wid][lane][k] = acc[k];
            }
        }
        __syncthreads();
        if (tid < 128) {
            float tot = 0.f;
#pragma unroll
            for (int w = 0; w < 16; ++w) tot += sh.it.psumA[w][tid >> 3][tid & 7];
            agent_stf(tpart + (size_t)(p * 8 + c) * 4096 + 128 * l + tid, tot);
        }

        // ---- B: prefetch private K (contiguous rows) before tpf chain ----
        const int r = tid >> 1, h = tid & 1;          // 2 threads/row, 64 cols each
        const u8* kb = K0 + (size_t)(512 * c + r) * NN + 128 * l + 64 * h;
        uint4 kq[4];
#pragma unroll
        for (int s4 = 0; s4 < 4; ++s4)
            kq[s4] = *(const uint4*)(kb + s4 * 16);

        publish(mytpf, n + 1, tid);                   // my stripe partial ready
        pollF<8>(tpf, n + 1, tid);                    // all 8 stripe partials ready
        if (tid < 128) {
            const float* tb = tpart + (size_t)p * 32768 + 128 * l + tid;
            float tq = 0.f;
#pragma unroll
            for (int cc = 0; cc < 8; ++cc) tq += agent_ldf(tb + cc * 4096);
            sh.it.vtl[tid] = 1.0f / tq;               // vt_j
        }
        __syncthreads();

        // ---- B compute: row partials s_i; coalesced parity store ----
        {
            float s = 0.f;
#pragma unroll
            for (int s4 = 0; s4 < 4; ++s4) {
                float qv[16];
                dec4(kq[s4].x, qv);      dec4(kq[s4].y, qv + 4);
                dec4(kq[s4].z, qv + 8);  dec4(kq[s4].w, qv + 12);
                const float* vp = &sh.it.vtl[64 * h + s4 * 16];
#pragma unroll
                for (int k = 0; k < 16; ++k) s = __fmaf_rn(qv[k], vp[k], s);
            }
            s += __shfl_xor(s, 1, 64);
            if (h == 0)   // even lanes: 32 consecutive floats per wave (coalesced)
                agent_stf(spart + (size_t)(p * 8 + c) * 16384 + l * 512 + r, s);
        }
        publish(myspf, n + 1, tid);                   // my chunk partial ready
    }

    // ------ F: loss = sum_ij K*(-eps log K)*ut_i*vt_j over own region ------
    // per element: (-eps/KSCL) * Q*(lnQ - 12ln2) * ut_i * vt_j
    pollF<32>(spf, NITER, tid);
    {
        const float* sp = spart + (size_t)(((NITER - 1) & 1) * 8 + c) * 16384;
        const int r = tid >> 1, h = tid & 1;
        float acc = 0.f;
#pragma unroll
        for (int lp = 0; lp < 16; ++lp)
            acc += agent_ldf(sp + (16 * h + lp) * 512 + r);
        acc += __shfl_xor(acc, 1, 64);
        if (h == 0) sh.it.uts[r] = 1.0f / acc;        // final ut
    }
    __syncthreads();
    {
        const int r = tid >> 1, h = tid & 1;
        const u8* kb = K0 + (size_t)(512 * c + r) * NN + 128 * l + 64 * h;
        uint4 kq[4];
#pragma unroll
        for (int s4 = 0; s4 < 4; ++s4)
            kq[s4] = *(const uint4*)(kb + s4 * 16);
        float a1 = 0.f, a2 = 0.f;
#pragma unroll
        for (int s4 = 0; s4 < 4; ++s4) {
            float qv[16];
            dec4(kq[s4].x, qv);      dec4(kq[s4].y, qv + 4);
            dec4(kq[s4].z, qv + 8);  dec4(kq[s4].w, qv + 12);
            const float* vp = &sh.it.vtl[64 * h + s4 * 16];
#pragma unroll
            for (int k = 0; k < 16; ++k) {
                const float q = qv[k];
                a2 = __fmaf_rn(q, vp[k], a2);
                a1 = __fmaf_rn(q * __logf(fmaxf(q, 1e-30f)), vp[k], a1);  // q=0 -> 0
            }
        }
        a1 += __shfl_xor(a1, 1, 64);
        a2 += __shfl_xor(a2, 1, 64);
        float rowv = (h == 0) ? (a1 - KLN2 * a2) * sh.it.uts[r] : 0.f;
        rowv = wsum(rowv);
        if (lane == 0) sh.it.psh[wid] = rowv;
    }
    __syncthreads();
    // ---- finale: 128-B-spaced tagged slots, one poller (no store convoy) ----
    if (tid == 0) {
        float bacc = 0.f;
#pragma unroll
        for (int w = 0; w < 16; ++w) bacc += sh.it.psh[w];
        asm volatile("s_waitcnt vmcnt(0)" ::: "memory");
        agent_st64(lossq + b * 16, pk(bacc, 1u));
        if (b == 0) {
            float tot;
            for (;;) {
                bool ok = true;
                float s = 0.f;
                for (int i = 0; i < NB; ++i) {
                    const u64 v = agent_ld64(lossq + i * 16);
                    ok &= (uptag(v) == 1u);
                    s += upv(v);
                }
                if (ok) { tot = s; break; }
                __builtin_amdgcn_s_sleep(1);
            }
            agent_stf(out, tot * (-REGE / KSCL));
        }
    }
}

extern "C" void kernel_launch(void* const* d_in, const int* in_sizes, int n_in,
                              void* d_out, int out_size, void* d_ws, size_t ws_size,
                              hipStream_t stream) {
    const float* x = (const float*)d_in[0];
    const float* y = (const float*)d_in[1];
    float* out = (float*)d_out;
    char* ws = (char*)d_ws;

    // ws: K0 e5m2 16MB | xsq,ysq 4096 f32 | tpart 2x8x4096 f32 | spart 2x8x32x512 f32
    //     | lossq 256 slots x 128 B | bar 16384 ints (flags, 128-B spaced)
    u8* K0 = (u8*)(ws);
    float* xsq = (float*)(ws + 16777216ull);
    float* ysq = xsq + 4096;
    float* tpart = ysq + 4096;             // 65536 floats (2 parities)
    float* spart = tpart + 65536;          // 262144 floats (2 parities)
    u64* lossq = (u64*)(spart + 262144);   // 256 x 16 u64 (128-B spacing)
    int* bar = (int*)(lossq + 4096);       // 16384 ints

    void* args[] = {&x, &y, &out, &K0, &xsq, &ysq, &tpart, &spart, &lossq, &bar};

    hipError_t err = hipLaunchCooperativeKernel((void*)sinkhorn_all, dim3(NB), dim3(1024),
                                                (void**)args, 0, stream);
    if (err != hipSuccess)
        (void)hipLaunchCooperativeKernel((void*)sinkhorn_all, dim3(NB), dim3(1024),
                                         (void**)args, 0, stream);
}